// Round 3
// baseline (212.958 us; speedup 1.0000x reference)
//
#include <hip/hip_runtime.h>

// GradientInputLayer: B=64, C=2, L=64, N=16, BIN=360//16=22, EPS=1e-5
// x: (64, 2*64^3) f32 in {0,1}; out: (64,2,16,16) f32
//
// ws layout: [0, 262144)          uint8 bin table tab[i*4096 + j*64 + k]
//            [262144, 393216)     float g[128*256] accumulator (pair-major)
//            [393216, 1441792)    float mag[262144] = sqrt(i^2+j^2+k^2) LUT
//
// R3: no device fences / nt loads per-block. R4: wave-privatization neutral.
// R5: pipelining neutral. R6: scatter 38.8us even x-L3-hot (not BW-bound).
// R7: fewer flushes only -3us. R8 diagnostic: hot-pass compute = 19.4us,
//   VALUBusy 34%, bank-conflicts 0 => cost was the branchy flush construct.
// R9: branch-free RLE via unconditional LDS slot writes; no hot-loop atomics.
// R10: mag LUT (hoisted 16 v_sqrt_f32 out of hot loop), byte-offset RLE,
//   float4 norm. 206 -> 197.6us. Harness resets (512MiB poison fill @78us +
//   x restore ~40us) dominate dur_us and are untouchable.
// R11: slot[256][10] was thread-major, row stride 20 dwords, gcd(20,32)=4
//   => ~8-way LDS bank conflict on every ds_write_b64. Transpose to
//   slot[SLOTS][256]: run steps 2048B == 0 mod 128B => bank = f(tid) only,
//   conflict-free both phases. nt loads on streamed-once x; 4-voxel
//   bin_table.
// R12: fix compile error — __builtin_nontemporal_load needs a native
//   clang vector type, not HIP_vector_type<float,4>. Load via
//   ext_vector_type(4) float (layout-identical) and bit-copy.

#define BINS_PAD 80   // real bins are 0..68 (ax,az in 0..4); 69 = flush sentinel
#define SLOTS 10      // ax,az both nondecreasing along k: <=8 changes/segment

typedef float fx4 __attribute__((ext_vector_type(4)));  // nt-load-compatible

__global__ __launch_bounds__(256)
void bin_table_kernel(uchar4* __restrict__ tab4,
                      float4* __restrict__ g4,
                      float4* __restrict__ mag4) {
    int t4 = blockIdx.x * 256 + threadIdx.x;         // 0..65535, 4 voxels each
    int v0 = t4 << 2;
    int i  = v0 >> 12;                               // constant over the 4
    int j  = (v0 >> 6) & 63;                         // constant over the 4
    int kb = v0 & 63;                                // 0,4,...,60
    double i2  = (double)(i * i);
    double zc2 = (double)(i * i + j * j);
    const double T1 = 0.4040262258351568  * 0.4040262258351568;
    const double T2 = 0.9656887748070740  * 0.9656887748070740;
    const double T3 = 2.2460367739042161  * 2.2460367739042161;
    const double T4 = 28.636253282915602  * 28.636253282915602;
    // Per-thread-constant products hoisted: 8 double muls total.
    double a1 = i2 * T1,  a2 = i2 * T2,  a3 = i2 * T3,  a4 = i2 * T4;
    double z1 = zc2 * T1, z2 = zc2 * T2, z3 = zc2 * T3, z4 = zc2 * T4;
    unsigned char tt[4];
    float         mm[4];
    float r2f = (float)(i * i + j * j);              // exact (< 2^24)
    #pragma unroll
    for (int e = 0; e < 4; ++e) {
        int k = kb + e;
        double xc2 = (double)(j * j + k * k);
        double k2  = (double)(k * k);
        // ax = floor(atan2(xc,i)*deg/22) == #{m : xc^2 > i^2 tan^2(22m)};
        // strict > handles every atan2 edge case exactly (absmax 0.0).
        int ax = (xc2 > a1) + (xc2 > a2) + (xc2 > a3) + (xc2 > a4);
        int az = (k2 > z1) + (k2 > z2) + (k2 > z3) + (k2 > z4);
        tt[e] = (unsigned char)(ax * 16 + az);
        float kf = (float)k;
        // EXACTLY the expression the scatter hot loop used to compute, so
        // values are bit-identical: sqrtf(fmaf(k, k, (float)(i*i+j*j))).
        mm[e] = sqrtf(fmaf(kf, kf, r2f));
    }
    uchar4 tb; tb.x = tt[0]; tb.y = tt[1]; tb.z = tt[2]; tb.w = tt[3];
    float4 mg; mg.x = mm[0]; mg.y = mm[1]; mg.z = mm[2]; mg.w = mm[3];
    tab4[t4] = tb;
    mag4[t4] = mg;
    if (t4 < 8192) {                                 // zero g (ws is poisoned)
        float4 z; z.x = 0.0f; z.y = 0.0f; z.z = 0.0f; z.w = 0.0f;
        g4[t4] = z;
    }
}

// Block = (pair p, i-slab), 256 threads. Thread owns j = tid>>2, k-segment
// (tid&3)*16..+15. Hot loop is 100% branch-free and atomic-free: per element,
// update (off, acc) with cndmask and UNCONDITIONALLY ds_write_b64
// (bin, acc) to slot[run][tid]. Since bin is monotone along k, each slot's
// final value is that run's complete sum. Slot layout is RUN-MAJOR
// [SLOTS][256]: run steps are 2048 B (bank-invariant), so LDS bank is a
// function of tid only => conflict-free. Phase 2 reduces slots -> hist;
// one <=80-bin global-atomic flush per block.
__global__ __launch_bounds__(256)
void scatter_kernel(const float4* __restrict__ x4,
                    const uint4* __restrict__ tab4,
                    const float4* __restrict__ mag4,
                    float* __restrict__ g) {
    __shared__ unsigned long long slot[SLOTS][256];   // 20 KB, run-major
    __shared__ float hist[BINS_PAD];
    int tid = threadIdx.x;
    int p   = blockIdx.x >> 6;               // (b,c) pair 0..127
    int i   = blockIdx.x & 63;               // i-slab 0..63

    // init own slots to sentinel (bin=69, acc=+0.0f) — no sync needed before
    // phase 1 (each thread touches only column tid)
    const unsigned long long SENT = ((unsigned long long)69u) << 32;
    #pragma unroll
    for (int s = 0; s < SLOTS; ++s) slot[s][tid] = SENT;
    if (tid < BINS_PAD) hist[tid] = 0.0f;

    // voxel float4 base for this thread: (j*64 + k0)/4 == 4*tid
    const fx4* xs = (const fx4*)x4 + (size_t)p * 65536 + (size_t)i * 1024 + 4 * (size_t)tid;
    const float4* ms = mag4 + (size_t)i * 1024 + 4 * (size_t)tid;   // L2-hot LUT
    uint4  tb  = tab4[i * 256 + tid];
    // x is streamed exactly once per iteration: nontemporal keeps it from
    // evicting the 1.25MB tab/mag tables out of per-XCD L2.
    fx4 nq0 = __builtin_nontemporal_load(xs + 0);
    fx4 nq1 = __builtin_nontemporal_load(xs + 1);
    fx4 nq2 = __builtin_nontemporal_load(xs + 2);
    fx4 nq3 = __builtin_nontemporal_load(xs + 3);
    float4 mq0 = ms[0], mq1 = ms[1], mq2 = ms[2], mq3 = ms[3];

    float4 xq[4];
    xq[0].x = nq0.x; xq[0].y = nq0.y; xq[0].z = nq0.z; xq[0].w = nq0.w;
    xq[1].x = nq1.x; xq[1].y = nq1.y; xq[1].z = nq1.z; xq[1].w = nq1.w;
    xq[2].x = nq2.x; xq[2].y = nq2.y; xq[2].z = nq2.z; xq[2].w = nq2.w;
    xq[3].x = nq3.x; xq[3].y = nq3.y; xq[3].z = nq3.z; xq[3].w = nq3.w;
    float4       mq[4] = {mq0, mq1, mq2, mq3};
    unsigned int uq[4] = {tb.x, tb.y, tb.z, tb.w};

    int          prev = -1;                  // != any bin => first write is run 0
    unsigned int off  = (unsigned int)(tid * 8) - 2048u;  // first bump -> row 0
    float        acc  = 0.0f;
    char* base = (char*)slot;

    #pragma unroll
    for (int q = 0; q < 4; ++q) {
        unsigned int u = uq[q];
        #pragma unroll
        for (int e = 0; e < 4; ++e) {
            float xe = (e == 0) ? xq[q].x : (e == 1) ? xq[q].y : (e == 2) ? xq[q].z : xq[q].w;
            float me = (e == 0) ? mq[q].x : (e == 1) ? mq[q].y : (e == 2) ? mq[q].z : mq[q].w;
            float val = xe * me;             // bitwise == xe*sqrtf(fmaf(k,k,r2f))
            int   b   = (u >> (8 * e)) & 255;
            bool  ch  = (b != prev);
            off += ch ? 2048u : 0u;          // advance one run-row
            acc  = ch ? val : (acc + val);
            prev = b;
            *(unsigned long long*)(base + off) =
                (((unsigned long long)(unsigned)b) << 32)
              | (unsigned long long)__float_as_uint(acc);
        }
    }
    __syncthreads();

    // phase 2: reduce this thread's slot column into the block hist
    #pragma unroll
    for (int s = 0; s < SLOTS; ++s) {
        unsigned long long pk = slot[s][tid];
        float av = __uint_as_float((unsigned int)pk);
        if (av != 0.0f) {
            unsigned int bb = (unsigned int)(pk >> 32);   // <= 69 < BINS_PAD
            atomicAdd(&hist[bb], av);
        }
    }
    __syncthreads();

    if (tid < BINS_PAD) {
        float hv = hist[tid];
        if (hv != 0.0f) atomicAdd(&g[p * 256 + tid], hv);
    }
}

// Single block: per-channel mean/var over (B, N, N) = 16384 values in double,
// then fused scale/shift write of all 32768 outputs. float4 path: 8 loads +
// 8 stores per thread (channel constant within a float4: c = (idx>>6)&1).
__global__ __launch_bounds__(1024)
void norm_kernel(const float4* __restrict__ g4,
                 const float* __restrict__ gamma,
                 const float* __restrict__ beta,
                 float4* __restrict__ out4) {
    __shared__ double red[16][4];
    __shared__ float  coef[4];        // sc0, sc1, sh0, sh1
    int t = threadIdx.x;
    float4 vals[8];
    double s0 = 0.0, s1 = 0.0, q0 = 0.0, q1 = 0.0;
    #pragma unroll
    for (int n = 0; n < 8; ++n) {
        int idx = t + n * 1024;                       // float4 index 0..8191
        float4 v = g4[idx];
        vals[n] = v;
        double a = (double)v.x + (double)v.y + (double)v.z + (double)v.w;
        double b = (double)v.x * (double)v.x + (double)v.y * (double)v.y
                 + (double)v.z * (double)v.z + (double)v.w * (double)v.w;
        if ((idx >> 6) & 1) { s1 += a; q1 += b; }
        else                { s0 += a; q0 += b; }
    }
    #pragma unroll
    for (int offm = 32; offm > 0; offm >>= 1) {
        s0 += __shfl_down(s0, offm);
        s1 += __shfl_down(s1, offm);
        q0 += __shfl_down(q0, offm);
        q1 += __shfl_down(q1, offm);
    }
    int wave = t >> 6;
    if ((t & 63) == 0) {
        red[wave][0] = s0; red[wave][1] = s1; red[wave][2] = q0; red[wave][3] = q1;
    }
    __syncthreads();
    if (t == 0) {
        double S0 = 0, S1 = 0, Q0 = 0, Q1 = 0;
        for (int wv = 0; wv < 16; ++wv) {
            S0 += red[wv][0]; S1 += red[wv][1]; Q0 += red[wv][2]; Q1 += red[wv][3];
        }
        const double inv_n = 1.0 / 16384.0;
        double m0 = S0 * inv_n, m1 = S1 * inv_n;
        double v0 = Q0 * inv_n - m0 * m0;
        double v1 = Q1 * inv_n - m1 * m1;
        double r0 = 1.0 / sqrt(v0 + 1e-5);
        double r1 = 1.0 / sqrt(v1 + 1e-5);
        float g0 = gamma[0], g1 = gamma[1], b0 = beta[0], b1 = beta[1];
        coef[0] = (float)r0 * g0;
        coef[1] = (float)r1 * g1;
        coef[2] = b0 - (float)(m0 * r0) * g0;
        coef[3] = b1 - (float)(m1 * r1) * g1;
    }
    __syncthreads();
    float sc0 = coef[0], sc1 = coef[1], sh0 = coef[2], sh1 = coef[3];
    #pragma unroll
    for (int n = 0; n < 8; ++n) {
        int idx = t + n * 1024;
        int c = (idx >> 6) & 1;
        float sc = c ? sc1 : sc0;
        float sh = c ? sh1 : sh0;
        float4 v = vals[n];
        float4 o;
        o.x = v.x * sc + sh; o.y = v.y * sc + sh;
        o.z = v.z * sc + sh; o.w = v.w * sc + sh;
        out4[idx] = o;
    }
}

extern "C" void kernel_launch(void* const* d_in, const int* in_sizes, int n_in,
                              void* d_out, int out_size, void* d_ws, size_t ws_size,
                              hipStream_t stream) {
    const float* x     = (const float*)d_in[0];
    const float* gamma = (const float*)d_in[1];
    const float* beta  = (const float*)d_in[2];
    float* out = (float*)d_out;

    unsigned char* tab = (unsigned char*)d_ws;
    float*         g   = (float*)((char*)d_ws + 262144);
    float*         mag = (float*)((char*)d_ws + 393216);

    bin_table_kernel<<<256, 256, 0, stream>>>((uchar4*)tab, (float4*)g, (float4*)mag);
    scatter_kernel<<<8192, 256, 0, stream>>>((const float4*)x, (const uint4*)tab,
                                             (const float4*)mag, g);
    norm_kernel<<<1, 1024, 0, stream>>>((const float4*)g, gamma, beta, (float4*)out);
}

// Round 4
// 197.482 us; speedup vs baseline: 1.0784x; 1.0784x over previous
//
#include <hip/hip_runtime.h>

// GradientInputLayer: B=64, C=2, L=64, N=16, BIN=360//16=22, EPS=1e-5
// x: (64, 2*64^3) f32 in {0,1}; out: (64,2,16,16) f32
//
// ws layout: [0, 262144)          uint8 bin table tab[i*4096 + j*64 + k]
//            [262144, 393216)     float g[128*256] accumulator (pair-major)
//            [393216, 1441792)    float mag[262144] = sqrt(i^2+j^2+k^2) LUT
//
// R3: no device fences / nt loads per-block. R4: wave-privatization neutral.
// R5: pipelining neutral. R6: scatter 38.8us even x-L3-hot (not BW-bound).
// R7: fewer flushes only -3us. R8 diagnostic: hot-pass compute = 19.4us,
//   VALUBusy 34%, bank-conflicts 0 => cost was the branchy flush construct.
// R9: branch-free RLE via unconditional LDS slot writes; no hot-loop atomics.
// R10: mag LUT (hoisted 16 v_sqrt_f32 out of hot loop), byte-offset RLE,
//   float4 norm. 206 -> 197.6us. Harness resets (512MiB poison fill @78us +
//   x restore ~40us) dominate dur_us and are untouchable.
// R11/R12: run-major slot[SLOTS][256] (bank = f(tid) only), 4-voxel
//   bin_table, nt loads on x. 197.6 -> 213.0us REGRESSION.
// R13 post-mortem: nt loads were the (re-)offender — x is restored每
//   iteration so it's L3-resident; nt forces HBM re-fetch (~+12-15us).
//   R3 had already rejected nt. Revert nt ONLY; keep transpose (at the
//   structural b64 bank floor) and 4-voxel bin_table. Expect ~195us.

#define BINS_PAD 80   // real bins are 0..68 (ax,az in 0..4); 69 = flush sentinel
#define SLOTS 10      // ax,az both nondecreasing along k: <=8 changes/segment

__global__ __launch_bounds__(256)
void bin_table_kernel(uchar4* __restrict__ tab4,
                      float4* __restrict__ g4,
                      float4* __restrict__ mag4) {
    int t4 = blockIdx.x * 256 + threadIdx.x;         // 0..65535, 4 voxels each
    int v0 = t4 << 2;
    int i  = v0 >> 12;                               // constant over the 4
    int j  = (v0 >> 6) & 63;                         // constant over the 4
    int kb = v0 & 63;                                // 0,4,...,60
    double i2  = (double)(i * i);
    double zc2 = (double)(i * i + j * j);
    const double T1 = 0.4040262258351568  * 0.4040262258351568;
    const double T2 = 0.9656887748070740  * 0.9656887748070740;
    const double T3 = 2.2460367739042161  * 2.2460367739042161;
    const double T4 = 28.636253282915602  * 28.636253282915602;
    // Per-thread-constant products hoisted: 8 double muls total.
    double a1 = i2 * T1,  a2 = i2 * T2,  a3 = i2 * T3,  a4 = i2 * T4;
    double z1 = zc2 * T1, z2 = zc2 * T2, z3 = zc2 * T3, z4 = zc2 * T4;
    unsigned char tt[4];
    float         mm[4];
    float r2f = (float)(i * i + j * j);              // exact (< 2^24)
    #pragma unroll
    for (int e = 0; e < 4; ++e) {
        int k = kb + e;
        double xc2 = (double)(j * j + k * k);
        double k2  = (double)(k * k);
        // ax = floor(atan2(xc,i)*deg/22) == #{m : xc^2 > i^2 tan^2(22m)};
        // strict > handles every atan2 edge case exactly (absmax 0.0).
        int ax = (xc2 > a1) + (xc2 > a2) + (xc2 > a3) + (xc2 > a4);
        int az = (k2 > z1) + (k2 > z2) + (k2 > z3) + (k2 > z4);
        tt[e] = (unsigned char)(ax * 16 + az);
        float kf = (float)k;
        // EXACTLY the expression the scatter hot loop used to compute, so
        // values are bit-identical: sqrtf(fmaf(k, k, (float)(i*i+j*j))).
        mm[e] = sqrtf(fmaf(kf, kf, r2f));
    }
    uchar4 tb; tb.x = tt[0]; tb.y = tt[1]; tb.z = tt[2]; tb.w = tt[3];
    float4 mg; mg.x = mm[0]; mg.y = mm[1]; mg.z = mm[2]; mg.w = mm[3];
    tab4[t4] = tb;
    mag4[t4] = mg;
    if (t4 < 8192) {                                 // zero g (ws is poisoned)
        float4 z; z.x = 0.0f; z.y = 0.0f; z.z = 0.0f; z.w = 0.0f;
        g4[t4] = z;
    }
}

// Block = (pair p, i-slab), 256 threads. Thread owns j = tid>>2, k-segment
// (tid&3)*16..+15. Hot loop is 100% branch-free and atomic-free: per element,
// update (off, acc) with cndmask and UNCONDITIONALLY ds_write_b64
// (bin, acc) to slot[run][tid]. Since bin is monotone along k, each slot's
// final value is that run's complete sum. Slot layout is RUN-MAJOR
// [SLOTS][256]: run steps are 2048 B (bank-invariant), so LDS bank is a
// function of tid only => at the structural wave64-b64 floor. Phase 2
// reduces slots -> hist; one <=80-bin global-atomic flush per block.
// Plain (cached) loads on x: it is harness-restored every iteration and
// therefore L3-resident — nt loads cost ~+15us (R12 regression, R3 repeat).
__global__ __launch_bounds__(256)
void scatter_kernel(const float4* __restrict__ x4,
                    const uint4* __restrict__ tab4,
                    const float4* __restrict__ mag4,
                    float* __restrict__ g) {
    __shared__ unsigned long long slot[SLOTS][256];   // 20 KB, run-major
    __shared__ float hist[BINS_PAD];
    int tid = threadIdx.x;
    int p   = blockIdx.x >> 6;               // (b,c) pair 0..127
    int i   = blockIdx.x & 63;               // i-slab 0..63

    // init own slots to sentinel (bin=69, acc=+0.0f) — no sync needed before
    // phase 1 (each thread touches only column tid)
    const unsigned long long SENT = ((unsigned long long)69u) << 32;
    #pragma unroll
    for (int s = 0; s < SLOTS; ++s) slot[s][tid] = SENT;
    if (tid < BINS_PAD) hist[tid] = 0.0f;

    // voxel float4 base for this thread: (j*64 + k0)/4 == 4*tid
    const float4* xs = x4 + (size_t)p * 65536 + (size_t)i * 1024 + 4 * (size_t)tid;
    const float4* ms = mag4 + (size_t)i * 1024 + 4 * (size_t)tid;   // L2-hot LUT
    uint4  tb  = tab4[i * 256 + tid];
    float4 xq0 = xs[0], xq1 = xs[1], xq2 = xs[2], xq3 = xs[3];
    float4 mq0 = ms[0], mq1 = ms[1], mq2 = ms[2], mq3 = ms[3];

    float4       xq[4] = {xq0, xq1, xq2, xq3};
    float4       mq[4] = {mq0, mq1, mq2, mq3};
    unsigned int uq[4] = {tb.x, tb.y, tb.z, tb.w};

    int          prev = -1;                  // != any bin => first write is run 0
    unsigned int off  = (unsigned int)(tid * 8) - 2048u;  // first bump -> row 0
    float        acc  = 0.0f;
    char* base = (char*)slot;

    #pragma unroll
    for (int q = 0; q < 4; ++q) {
        unsigned int u = uq[q];
        #pragma unroll
        for (int e = 0; e < 4; ++e) {
            float xe = (e == 0) ? xq[q].x : (e == 1) ? xq[q].y : (e == 2) ? xq[q].z : xq[q].w;
            float me = (e == 0) ? mq[q].x : (e == 1) ? mq[q].y : (e == 2) ? mq[q].z : mq[q].w;
            float val = xe * me;             // bitwise == xe*sqrtf(fmaf(k,k,r2f))
            int   b   = (u >> (8 * e)) & 255;
            bool  ch  = (b != prev);
            off += ch ? 2048u : 0u;          // advance one run-row
            acc  = ch ? val : (acc + val);
            prev = b;
            *(unsigned long long*)(base + off) =
                (((unsigned long long)(unsigned)b) << 32)
              | (unsigned long long)__float_as_uint(acc);
        }
    }
    __syncthreads();

    // phase 2: reduce this thread's slot column into the block hist
    #pragma unroll
    for (int s = 0; s < SLOTS; ++s) {
        unsigned long long pk = slot[s][tid];
        float av = __uint_as_float((unsigned int)pk);
        if (av != 0.0f) {
            unsigned int bb = (unsigned int)(pk >> 32);   // <= 69 < BINS_PAD
            atomicAdd(&hist[bb], av);
        }
    }
    __syncthreads();

    if (tid < BINS_PAD) {
        float hv = hist[tid];
        if (hv != 0.0f) atomicAdd(&g[p * 256 + tid], hv);
    }
}

// Single block: per-channel mean/var over (B, N, N) = 16384 values in double,
// then fused scale/shift write of all 32768 outputs. float4 path: 8 loads +
// 8 stores per thread (channel constant within a float4: c = (idx>>6)&1).
__global__ __launch_bounds__(1024)
void norm_kernel(const float4* __restrict__ g4,
                 const float* __restrict__ gamma,
                 const float* __restrict__ beta,
                 float4* __restrict__ out4) {
    __shared__ double red[16][4];
    __shared__ float  coef[4];        // sc0, sc1, sh0, sh1
    int t = threadIdx.x;
    float4 vals[8];
    double s0 = 0.0, s1 = 0.0, q0 = 0.0, q1 = 0.0;
    #pragma unroll
    for (int n = 0; n < 8; ++n) {
        int idx = t + n * 1024;                       // float4 index 0..8191
        float4 v = g4[idx];
        vals[n] = v;
        double a = (double)v.x + (double)v.y + (double)v.z + (double)v.w;
        double b = (double)v.x * (double)v.x + (double)v.y * (double)v.y
                 + (double)v.z * (double)v.z + (double)v.w * (double)v.w;
        if ((idx >> 6) & 1) { s1 += a; q1 += b; }
        else                { s0 += a; q0 += b; }
    }
    #pragma unroll
    for (int offm = 32; offm > 0; offm >>= 1) {
        s0 += __shfl_down(s0, offm);
        s1 += __shfl_down(s1, offm);
        q0 += __shfl_down(q0, offm);
        q1 += __shfl_down(q1, offm);
    }
    int wave = t >> 6;
    if ((t & 63) == 0) {
        red[wave][0] = s0; red[wave][1] = s1; red[wave][2] = q0; red[wave][3] = q1;
    }
    __syncthreads();
    if (t == 0) {
        double S0 = 0, S1 = 0, Q0 = 0, Q1 = 0;
        for (int wv = 0; wv < 16; ++wv) {
            S0 += red[wv][0]; S1 += red[wv][1]; Q0 += red[wv][2]; Q1 += red[wv][3];
        }
        const double inv_n = 1.0 / 16384.0;
        double m0 = S0 * inv_n, m1 = S1 * inv_n;
        double v0 = Q0 * inv_n - m0 * m0;
        double v1 = Q1 * inv_n - m1 * m1;
        double r0 = 1.0 / sqrt(v0 + 1e-5);
        double r1 = 1.0 / sqrt(v1 + 1e-5);
        float g0 = gamma[0], g1 = gamma[1], b0 = beta[0], b1 = beta[1];
        coef[0] = (float)r0 * g0;
        coef[1] = (float)r1 * g1;
        coef[2] = b0 - (float)(m0 * r0) * g0;
        coef[3] = b1 - (float)(m1 * r1) * g1;
    }
    __syncthreads();
    float sc0 = coef[0], sc1 = coef[1], sh0 = coef[2], sh1 = coef[3];
    #pragma unroll
    for (int n = 0; n < 8; ++n) {
        int idx = t + n * 1024;
        int c = (idx >> 6) & 1;
        float sc = c ? sc1 : sc0;
        float sh = c ? sh1 : sh0;
        float4 v = vals[n];
        float4 o;
        o.x = v.x * sc + sh; o.y = v.y * sc + sh;
        o.z = v.z * sc + sh; o.w = v.w * sc + sh;
        out4[idx] = o;
    }
}

extern "C" void kernel_launch(void* const* d_in, const int* in_sizes, int n_in,
                              void* d_out, int out_size, void* d_ws, size_t ws_size,
                              hipStream_t stream) {
    const float* x     = (const float*)d_in[0];
    const float* gamma = (const float*)d_in[1];
    const float* beta  = (const float*)d_in[2];
    float* out = (float*)d_out;

    unsigned char* tab = (unsigned char*)d_ws;
    float*         g   = (float*)((char*)d_ws + 262144);
    float*         mag = (float*)((char*)d_ws + 393216);

    bin_table_kernel<<<256, 256, 0, stream>>>((uchar4*)tab, (float4*)g, (float4*)mag);
    scatter_kernel<<<8192, 256, 0, stream>>>((const float4*)x, (const uint4*)tab,
                                             (const float4*)mag, g);
    norm_kernel<<<1, 1024, 0, stream>>>((const float4*)g, gamma, beta, (float4*)out);
}